// Round 6
// baseline (107.984 us; speedup 1.0000x reference)
//
#include <hip/hip_runtime.h>

// Additive (Bahdanau) attention, fp32 in/out.
// B=2, L=512, S=512, H=8, E=32, D=64.
// scores[b,h,l,s] = sum_e tanh(q[b,l,h,e] + k[b,s,h,e]) * v[e]  (+ masks)
// A = softmax_s(scores); out[b,l,h,d] = sum_s A * values[b,s,h,d]
//
// tanh(x) = 1 - 2/(exp2(SC*x)+1), SC = 2*log2(e);
// exp2(SC*(q+k)) = exp2(SC*q)*exp2(SC*k). Inner (l,s,e) loop: fma+rcp+fma.
//
// R6: launch-invariant transforms hoisted into a prep kernel writing d_ws:
//   ws_ek: exp2(SC*k) pre-swizzled into the LDS tile image (staging = copy)
//   ws_eq: exp2(SC*q)
//   ws_vt: V^T as bf16 (B,H,D,S) -> phase-3 B-frag = 1 global_load_dwordx4
// Main kernel keeps R5's high-TLP shape (1 row/wave, TS=128, 2048 blocks,
// ~52 VGPR). LDS trimmed to exactly 20480 B -> 8 blocks/CU cap.

#define BB 2
#define LL 512
#define SS 512
#define HH 8
#define EE 32
#define DD 64
#define TS 128

// d_ws layout (bytes):
//   [0, 2M)   ws_ek : float4[B][H][4 tiles][8 e4][128 u], u = ss^e4
//   [2M, 4M)  ws_eq : float  [B][L][H][E]  (same linear layout as q)
//   [4M, 5M)  ws_vt : ushort [B][H][D][S]  (bf16)
#define WS_EK_OFF 0
#define WS_EQ_OFF (2u * 1024u * 1024u)
#define WS_VT_OFF (4u * 1024u * 1024u)

typedef __attribute__((ext_vector_type(8))) short bf16x8;
typedef __attribute__((ext_vector_type(4))) float f32x4;

__device__ __forceinline__ unsigned short f2bf(float f) {   // fp32->bf16 RNE
    unsigned u = __float_as_uint(f);
    u += 0x7FFFu + ((u >> 16) & 1u);
    return (unsigned short)(u >> 16);
}
__device__ __forceinline__ float fast_exp2(float x) {
#if __has_builtin(__builtin_amdgcn_exp2f)
    return __builtin_amdgcn_exp2f(x);
#else
    return exp2f(x);
#endif
}
__device__ __forceinline__ float fast_rcp(float x) {
    return __builtin_amdgcn_rcpf(x);
}

#define SCV 2.885390081777927f   // 2*log2(e)

// ---------------- prep kernel: 1536 blocks x 256 ----------------
// blocks [0,256):    ws_ek  (65536 float4 tasks)
// blocks [256,512):  ws_eq  (65536 float4 tasks)
// blocks [512,1536): ws_vt  (262144 bf16-pair tasks)
__global__ __launch_bounds__(256) void prep_kernel(
    const float* __restrict__ q, const float* __restrict__ k,
    const float* __restrict__ vals, float* __restrict__ ws)
{
    unsigned gid = blockIdx.x * 256 + threadIdx.x;
    if (gid < 65536u) {
        // ek image: i = [b][h][t][e4][u], value = exp2(SC*k[b][t*128+(u^e4)][h][e4*4..])
        unsigned i  = gid;
        unsigned u  = i & 127u;
        unsigned e4 = (i >> 7) & 7u;
        unsigned t  = (i >> 10) & 3u;
        unsigned h  = (i >> 12) & 7u;
        unsigned b  = i >> 15;
        unsigned s  = t * 128u + (u ^ e4);
        float4 kv = *(const float4*)(k + (((size_t)b * SS + s) * HH + h) * EE + e4 * 4);
        float4 ev = make_float4(fast_exp2(SCV * kv.x), fast_exp2(SCV * kv.y),
                                fast_exp2(SCV * kv.z), fast_exp2(SCV * kv.w));
        ((float4*)(ws + WS_EK_OFF / 4))[i] = ev;
    } else if (gid < 131072u) {
        unsigned i = gid - 65536u;   // eq: elementwise, same linear layout as q
        float4 qv = ((const float4*)q)[i];
        float4 ev = make_float4(fast_exp2(SCV * qv.x), fast_exp2(SCV * qv.y),
                                fast_exp2(SCV * qv.z), fast_exp2(SCV * qv.w));
        ((float4*)(ws + WS_EQ_OFF / 4))[i] = ev;
    } else {
        // vt: p = [b][h][sp][d], writes bf16 pair (s=2sp, 2sp+1) at vt[b][h][d][2sp..]
        unsigned p  = gid - 131072u;
        unsigned d  = p & 63u;
        unsigned sp = (p >> 6) & 255u;
        unsigned h  = (p >> 14) & 7u;
        unsigned b  = p >> 17;
        unsigned s0 = sp * 2u;
        float f0 = vals[(((size_t)b * SS + s0) * HH + h) * DD + d];
        float f1 = vals[(((size_t)b * SS + s0 + 1) * HH + h) * DD + d];
        unsigned pk = (unsigned)f2bf(f0) | ((unsigned)f2bf(f1) << 16);
        unsigned* vt = (unsigned*)((char*)ws + WS_VT_OFF);
        vt[(((size_t)b * HH + h) * DD + d) * (SS / 2) + sp] = pk;
    }
}

// ---------------- main kernel: 2048 blocks x 256 ----------------
__global__ __launch_bounds__(256) void addattn_kernel(
    const float* __restrict__ ws_ekf,   // pre-swizzled ek tiles (float4 image)
    const float* __restrict__ ws_eqf,   // exp2(SC*q)
    const unsigned short* __restrict__ ws_vt,  // V^T bf16 (B,H,D,S)
    const float* __restrict__ mask,     // (L,S)
    const float* __restrict__ klen,     // (B,S)
    float* __restrict__ out)            // (B,L,H,D)
{
    __shared__ float4 sk[EE / 4][TS];   // 16384 B, pre-swizzled ek tile
    __shared__ short  sAb[4][SS];       // 4096 B bf16 probs; total 20480 B

    const int tid  = threadIdx.x;
    const int w    = tid >> 6;
    const int lane = tid & 63;
    const int bh   = blockIdx.x >> 7;
    const int lblk = blockIdx.x & 127;
    const int b    = bh >> 3;
    const int h    = bh & 7;
    const int l    = lblk * 4 + w;

    // eq for this wave's row (wave-uniform broadcast loads, no exp2)
    float4 eq[EE / 4];
    {
        const float4* qrow =
            (const float4*)(ws_eqf + (((size_t)b * LL + l) * HH + h) * EE);
        #pragma unroll
        for (int e4 = 0; e4 < EE / 4; e4++) eq[e4] = qrow[e4];
    }
    // Note: v2 = -2*v is folded per-element below; v itself loaded once.
    float4 v2[EE / 4];
    {
        // vvec passed via mask pointer arithmetic? No — passed separately:
        // (v2 filled in kernel_launch-provided vvec — see extra param trick)
    }
    // v2 is provided through klen? cleaner: vvec is its own param (below).
    (void)v2;

    // --- the above placeholder removed; real code continues in addattn2 ---
    (void)sk; (void)sAb; (void)eq; (void)ws_vt; (void)mask; (void)klen;
    (void)out; (void)lane; (void)b; (void)h; (void)l;
}

// Real main kernel (single definition used below).
__global__ __launch_bounds__(256) void addattn2_kernel(
    const float* __restrict__ ws_ekf,
    const float* __restrict__ ws_eqf,
    const unsigned short* __restrict__ ws_vt,
    const float* __restrict__ vvec,     // (E)
    const float* __restrict__ mask,     // (L,S)
    const float* __restrict__ klen,     // (B,S)
    float* __restrict__ out)            // (B,L,H,D)
{
    __shared__ float4 sk[EE / 4][TS];   // 16384 B
    __shared__ short  sAb[4][SS];       // 4096 B  (total 20480 -> 8 blocks/CU)

    const int tid  = threadIdx.x;
    const int w    = tid >> 6;
    const int lane = tid & 63;
    const int bh   = blockIdx.x >> 7;
    const int lblk = blockIdx.x & 127;
    const int b    = bh >> 3;
    const int h    = bh & 7;
    const int l    = lblk * 4 + w;

    float4 eq[EE / 4];
    {
        const float4* qrow =
            (const float4*)(ws_eqf + (((size_t)b * LL + l) * HH + h) * EE);
        #pragma unroll
        for (int e4 = 0; e4 < EE / 4; e4++) eq[e4] = qrow[e4];
    }
    float4 v2[EE / 4];
    {
        const float4* vr = (const float4*)vvec;
        #pragma unroll
        for (int i = 0; i < EE / 4; i++) {
            float4 t = vr[i];
            v2[i] = make_float4(-2.f * t.x, -2.f * t.y, -2.f * t.z, -2.f * t.w);
        }
    }

    // ---- Phase 1: scores; staging is a pure 16 KB copy (pre-swizzled). ----
    float sc[SS / 64];
    const float4* ektiles =
        (const float4*)ws_ekf + ((size_t)(b * HH + h) * 4) * (8 * TS);
    float4* skl = &sk[0][0];
    for (int t = 0; t < SS / TS; t++) {
        __syncthreads();
        const float4* src = ektiles + (size_t)t * (8 * TS);
        #pragma unroll
        for (int i = 0; i < 4; i++)
            skl[tid + i * 256] = src[tid + i * 256];
        __syncthreads();
        #pragma unroll
        for (int j = 0; j < 2; j++) {
            int ssl = lane + j * 64;
            float a0 = 0.f, a1 = 0.f, a2 = 0.f, a3 = 0.f;
            #pragma unroll
            for (int e4 = 0; e4 < EE / 4; e4++) {
                float4 kv = sk[e4][ssl ^ e4];   // conflict-free ds_read_b128
                float4 ev = eq[e4];
                float4 vv = v2[e4];
                a0 = __builtin_fmaf(vv.x, fast_rcp(__builtin_fmaf(ev.x, kv.x, 1.f)), a0);
                a1 = __builtin_fmaf(vv.y, fast_rcp(__builtin_fmaf(ev.y, kv.y, 1.f)), a1);
                a2 = __builtin_fmaf(vv.z, fast_rcp(__builtin_fmaf(ev.z, kv.z, 1.f)), a2);
                a3 = __builtin_fmaf(vv.w, fast_rcp(__builtin_fmaf(ev.w, kv.w, 1.f)), a3);
            }
            sc[t * 2 + j] = (a0 + a1) + (a2 + a3);
        }
    }

    // ---- Phase 2: masks + per-wave softmax, probs -> LDS bf16. ----
    {
        const float* mrow = mask + (size_t)l * SS;
        const float* kl   = klen + (size_t)b * SS;
        float mx = -1e30f;
        #pragma unroll
        for (int i = 0; i < SS / 64; i++) {
            int s = lane + i * 64;
            sc[i] += mrow[s] + kl[s];
            mx = fmaxf(mx, sc[i]);
        }
        #pragma unroll
        for (int off = 1; off < 64; off <<= 1) mx = fmaxf(mx, __shfl_xor(mx, off, 64));
        float ssum = 0.f;
        #pragma unroll
        for (int i = 0; i < SS / 64; i++) {
            sc[i] = __expf(sc[i] - mx);
            ssum += sc[i];
        }
        #pragma unroll
        for (int off = 1; off < 64; off <<= 1) ssum += __shfl_xor(ssum, off, 64);
        float inv = fast_rcp(ssum);
        #pragma unroll
        for (int i = 0; i < SS / 64; i++)
            sAb[w][lane + i * 64] = (short)f2bf(sc[i] * inv);
    }
    __syncthreads();

    // ---- Phase 3: PV via MFMA; B-frags = 1 dwordx4 bf16 load each. ----
    const int am  = lane & 15;
    const int qd  = lane >> 4;
    const int dof = w * 16 + am;
    const unsigned short* vt =
        ws_vt + (((size_t)b * HH + h) * DD + dof) * SS + qd * 8;
    f32x4 acc = {0.f, 0.f, 0.f, 0.f};
    bf16x8 bcur = *(const bf16x8*)vt;
    for (int c = 0; c < SS / 32; c++) {
        bf16x8 bnxt = bcur;
        if (c < SS / 32 - 1) bnxt = *(const bf16x8*)(vt + (c + 1) * 32);
        bf16x8 af = {0, 0, 0, 0, 0, 0, 0, 0};
        if (am < 4) af = *(const bf16x8*)&sAb[am][c * 32 + qd * 8];
        acc = __builtin_amdgcn_mfma_f32_16x16x32_bf16(af, bcur, acc, 0, 0, 0);
        bcur = bnxt;
    }
    // C layout: col = lane&15 (d), row = qd*4 + reg; valid rows -> qd==0
    if (qd == 0) {
        float* orow = out + (((size_t)b * LL + lblk * 4) * HH + h) * DD + dof;
        #pragma unroll
        for (int r = 0; r < 4; r++)
            orow[(size_t)r * (HH * DD)] = acc[r];
    }
}

extern "C" void kernel_launch(void* const* d_in, const int* in_sizes, int n_in,
                              void* d_out, int out_size, void* d_ws, size_t ws_size,
                              hipStream_t stream) {
    const float* q    = (const float*)d_in[0];
    const float* k    = (const float*)d_in[1];
    const float* vals = (const float*)d_in[2];
    const float* vvec = (const float*)d_in[3];
    const float* mask = (const float*)d_in[4];
    const float* klen = (const float*)d_in[5];
    float* outp = (float*)d_out;

    float* ws = (float*)d_ws;
    prep_kernel<<<dim3(1536), dim3(256), 0, stream>>>(q, k, vals, ws);

    const float* ws_ekf = (const float*)((char*)d_ws + WS_EK_OFF);
    const float* ws_eqf = (const float*)((char*)d_ws + WS_EQ_OFF);
    const unsigned short* ws_vt = (const unsigned short*)((char*)d_ws + WS_VT_OFF);
    addattn2_kernel<<<dim3(BB * HH * (LL / 4)), dim3(256), 0, stream>>>(
        ws_ekf, ws_eqf, ws_vt, vvec, mask, klen, outp);
}

// Round 7
// 97.392 us; speedup vs baseline: 1.1088x; 1.1088x over previous
//
#include <hip/hip_runtime.h>

// Additive (Bahdanau) attention, fp32 in/out.
// B=2, L=512, S=512, H=8, E=32, D=64.
// scores[b,h,l,s] = sum_e tanh(q[b,l,h,e] + k[b,s,h,e]) * v[e]  (+ masks)
// A = softmax_s(scores); out[b,l,h,d] = sum_s A * values[b,s,h,d]
//
// tanh(x) = 1 - 2/(exp2(SC*x)+1), SC = 2*log2(e);
// exp2(SC*(q+k)) = exp2(SC*q)*exp2(SC*k). Inner (l,s,e) loop: fma+rcp+fma.
// Prep kernel precomputes ws_ek (exp2(SC*k), pre-swizzled LDS tile image),
// ws_eq (exp2(SC*q)), ws_vt (V^T bf16 (B,H,D,S)).
//
// R6 lessons: (1) unpadded sAb -> 1.57M bank-conflict cycles (4 rows alias
// same banks) -> fixed by XOR-chunk swizzle, zero LDS cost. (2) staging
// global latency sat inside a sync/load/sync sandwich -> double-buffered
// TS=64 tiles with register prefetch, 1 barrier/tile, latency covered by
// compute. LDS stays exactly 20480 B -> 8 blocks/CU. VGPR must stay <=64.

#define BB 2
#define LL 512
#define SS 512
#define HH 8
#define EE 32
#define DD 64
#define TS 64           // s-tile per buffer (double-buffered)
#define NT (SS / TS)    // 8 tiles

// d_ws layout (bytes):
//   [0, 2M)   ws_ek : float4[B][H][8 tiles][8 e4][64 u], u = ssl^e4
//   [2M, 4M)  ws_eq : float  [B][L][H][E]
//   [4M, 5M)  ws_vt : ushort [B][H][D][S]  (bf16)
#define WS_EK_OFF 0
#define WS_EQ_OFF (2u * 1024u * 1024u)
#define WS_VT_OFF (4u * 1024u * 1024u)

typedef __attribute__((ext_vector_type(8))) short bf16x8;
typedef __attribute__((ext_vector_type(4))) float f32x4;
typedef __attribute__((ext_vector_type(4))) unsigned u32x4;

__device__ __forceinline__ unsigned short f2bf(float f) {   // fp32->bf16 RNE
    unsigned u = __float_as_uint(f);
    u += 0x7FFFu + ((u >> 16) & 1u);
    return (unsigned short)(u >> 16);
}
__device__ __forceinline__ float fast_exp2(float x) {
#if __has_builtin(__builtin_amdgcn_exp2f)
    return __builtin_amdgcn_exp2f(x);
#else
    return exp2f(x);
#endif
}
__device__ __forceinline__ float fast_rcp(float x) {
    return __builtin_amdgcn_rcpf(x);
}

#define SCV 2.885390081777927f   // 2*log2(e)

// ---------------- prep kernel: 768 blocks x 256 ----------------
// blocks [0,256):   ws_ek (65536 float4 tasks)
// blocks [256,512): ws_eq (65536 float4 tasks)
// blocks [512,768): ws_vt (65536 tasks, 8 s-values -> one 16B store)
__global__ __launch_bounds__(256) void prep_kernel(
    const float* __restrict__ q, const float* __restrict__ k,
    const float* __restrict__ vals, float* __restrict__ ws)
{
    unsigned gid = blockIdx.x * 256 + threadIdx.x;
    if (gid < 65536u) {
        // ek image: i = [b][h][t:8][e4:8][u:64], val = exp2(SC*k[b][t*64+(u^e4)][h][4e4..])
        unsigned i  = gid;
        unsigned u  = i & 63u;
        unsigned e4 = (i >> 6) & 7u;
        unsigned t  = (i >> 9) & 7u;
        unsigned h  = (i >> 12) & 7u;
        unsigned b  = i >> 15;
        unsigned s  = t * 64u + (u ^ e4);
        float4 kv = *(const float4*)(k + (((size_t)b * SS + s) * HH + h) * EE + e4 * 4);
        float4 ev = make_float4(fast_exp2(SCV * kv.x), fast_exp2(SCV * kv.y),
                                fast_exp2(SCV * kv.z), fast_exp2(SCV * kv.w));
        ((float4*)(ws + WS_EK_OFF / 4))[i] = ev;
    } else if (gid < 131072u) {
        unsigned i = gid - 65536u;   // eq: elementwise, q's linear layout
        float4 qv = ((const float4*)q)[i];
        float4 ev = make_float4(fast_exp2(SCV * qv.x), fast_exp2(SCV * qv.y),
                                fast_exp2(SCV * qv.z), fast_exp2(SCV * qv.w));
        ((float4*)(ws + WS_EQ_OFF / 4))[i] = ev;
    } else {
        // vt: p = [b][h][d][sp8]; thread packs s = 8*sp8..8*sp8+7 for one d
        // -> one 16B store, contiguous across consecutive threads.
        unsigned p   = gid - 131072u;
        unsigned sp8 = p & 63u;
        unsigned d   = (p >> 6) & 63u;
        unsigned h   = (p >> 12) & 7u;
        unsigned b   = p >> 15;
        unsigned s0  = sp8 * 8u;
        const float* vb = vals + (((size_t)b * SS + s0) * HH + h) * DD + d;
        u32x4 pk;
        #pragma unroll
        for (int j = 0; j < 4; j++) {
            float f0 = vb[(size_t)(2 * j) * (HH * DD)];
            float f1 = vb[(size_t)(2 * j + 1) * (HH * DD)];
            pk[j] = (unsigned)f2bf(f0) | ((unsigned)f2bf(f1) << 16);
        }
        u32x4* vt4 = (u32x4*)((char*)ws + WS_VT_OFF);
        vt4[((((size_t)b * HH + h) * DD + d) * SS + s0) / 8] = pk;
    }
}

// ---------------- main kernel: 2048 blocks x 256 ----------------
__global__ __launch_bounds__(256) void addattn_kernel(
    const float* __restrict__ ws_ekf,          // pre-swizzled ek tile images
    const float* __restrict__ ws_eqf,          // exp2(SC*q)
    const unsigned short* __restrict__ ws_vt,  // V^T bf16 (B,H,D,S)
    const float* __restrict__ vvec,            // (E)
    const float* __restrict__ mask,            // (L,S)
    const float* __restrict__ klen,            // (B,S)
    float* __restrict__ out)                   // (B,L,H,D)
{
    __shared__ float4 sk[2][EE / 4][TS];       // 2 x 8 KB, double-buffered
    __shared__ unsigned short sAb[4][SS];      // 4 KB; total 20480 -> 8 blk/CU

    const int tid  = threadIdx.x;
    const int w    = tid >> 6;
    const int lane = tid & 63;
    const int bh   = blockIdx.x >> 7;
    const int lblk = blockIdx.x & 127;
    const int b    = bh >> 3;
    const int h    = bh & 7;
    const int l    = lblk * 4 + w;

    // eq / v2: lane-uniform -> compiler scalarizes into SGPRs (R6: VGPR=52)
    float4 eq[EE / 4];
    {
        const float4* qrow =
            (const float4*)(ws_eqf + (((size_t)b * LL + l) * HH + h) * EE);
        #pragma unroll
        for (int e4 = 0; e4 < EE / 4; e4++) eq[e4] = qrow[e4];
    }
    float4 v2[EE / 4];
    {
        const float4* vr = (const float4*)vvec;
        #pragma unroll
        for (int i = 0; i < EE / 4; i++) {
            float4 t = vr[i];
            v2[i] = make_float4(-2.f * t.x, -2.f * t.y, -2.f * t.z, -2.f * t.w);
        }
    }

    // ---- Phase 1: double-buffered tiles, 1 barrier/tile. ----
    // Tile image: 512 float4 = [e4:8][u:64]; staging = pure copy (2/thread).
    const float4* ektiles =
        (const float4*)ws_ekf + (size_t)(b * HH + h) * (NT * 8 * TS);
    {
        float4 p0 = ektiles[tid];
        float4 p1 = ektiles[tid + 256];
        float4* dst = (float4*)sk[0];
        dst[tid] = p0;
        dst[tid + 256] = p1;
    }
    __syncthreads();

    float sc[NT];
    for (int t = 0; t < NT; t++) {
        float4 n0, n1;
        if (t < NT - 1) {                       // prefetch next tile (regs)
            const float4* src = ektiles + (size_t)(t + 1) * (8 * TS);
            n0 = src[tid];
            n1 = src[tid + 256];
        }
        const int buf = t & 1;
        {
            float a0 = 0.f, a1 = 0.f, a2 = 0.f, a3 = 0.f;  // 4 indep chains
            #pragma unroll
            for (int e4 = 0; e4 < EE / 4; e4++) {
                float4 kv = sk[buf][e4][lane ^ e4];  // measured conflict-free
                float4 ev = eq[e4];
                float4 vv = v2[e4];
                a0 = __builtin_fmaf(vv.x, fast_rcp(__builtin_fmaf(ev.x, kv.x, 1.f)), a0);
                a1 = __builtin_fmaf(vv.y, fast_rcp(__builtin_fmaf(ev.y, kv.y, 1.f)), a1);
                a2 = __builtin_fmaf(vv.z, fast_rcp(__builtin_fmaf(ev.z, kv.z, 1.f)), a2);
                a3 = __builtin_fmaf(vv.w, fast_rcp(__builtin_fmaf(ev.w, kv.w, 1.f)), a3);
            }
            sc[t] = (a0 + a1) + (a2 + a3);
        }
        if (t < NT - 1) {                       // write prefetch to other buf
            float4* dst = (float4*)sk[buf ^ 1];
            dst[tid] = n0;
            dst[tid + 256] = n1;
        }
        __syncthreads();   // protects buf reuse; vmcnt covered by compute
    }

    // ---- Phase 2: masks + per-wave softmax -> sAb (bf16, chunk-swizzled) --
    // 16B chunk cc of row r stored at chunk (cc ^ ((r*5)&7)): phase-3 reads
    // land 2 lanes/bank (free); writes stay 8-chunk contiguous per iter.
    {
        const float* mrow = mask + (size_t)l * SS;
        const float* kl   = klen + (size_t)b * SS;
        float mx = -1e30f;
        #pragma unroll
        for (int i = 0; i < SS / 64; i++) {
            int s = lane + i * 64;
            sc[i] += mrow[s] + kl[s];
            mx = fmaxf(mx, sc[i]);
        }
        #pragma unroll
        for (int off = 1; off < 64; off <<= 1) mx = fmaxf(mx, __shfl_xor(mx, off, 64));
        float ssum = 0.f;
        #pragma unroll
        for (int i = 0; i < SS / 64; i++) {
            sc[i] = __expf(sc[i] - mx);
            ssum += sc[i];
        }
        #pragma unroll
        for (int off = 1; off < 64; off <<= 1) ssum += __shfl_xor(ssum, off, 64);
        float inv = fast_rcp(ssum);
        const int fsw = (w * 5) & 7;           // wave-uniform row swizzle
        #pragma unroll
        for (int i = 0; i < SS / 64; i++) {
            int col = lane + i * 64;
            int pos = (((col >> 3) ^ fsw) << 3) | (col & 7);
            sAb[w][pos] = f2bf(sc[i] * inv);
        }
    }
    __syncthreads();

    // ---- Phase 3: PV via MFMA; B-frag = 1 bf16x8 load from ws_vt. ----
    const int am  = lane & 15;
    const int qd  = lane >> 4;
    const int dof = w * 16 + am;
    const int fam = (am * 5) & 7;              // A-row swizzle
    const unsigned short* vt =
        ws_vt + (((size_t)b * HH + h) * DD + dof) * SS + qd * 8;
    f32x4 acc = {0.f, 0.f, 0.f, 0.f};
    bf16x8 bcur = *(const bf16x8*)vt;
    for (int c = 0; c < SS / 32; c++) {
        bf16x8 bnxt = bcur;
        if (c < SS / 32 - 1) bnxt = *(const bf16x8*)(vt + (c + 1) * 32);
        bf16x8 af = {0, 0, 0, 0, 0, 0, 0, 0};
        if (am < 4)
            af = *(const bf16x8*)&sAb[am][((c * 4 + qd) ^ fam) << 3];
        acc = __builtin_amdgcn_mfma_f32_16x16x32_bf16(af, bcur, acc, 0, 0, 0);
        bcur = bnxt;
    }
    // C layout: col = lane&15 (d), row = qd*4 + reg; valid rows -> qd==0
    if (qd == 0) {
        float* orow = out + (((size_t)b * LL + lblk * 4) * HH + h) * DD + dof;
        #pragma unroll
        for (int r = 0; r < 4; r++)
            orow[(size_t)r * (HH * DD)] = acc[r];
    }
}

extern "C" void kernel_launch(void* const* d_in, const int* in_sizes, int n_in,
                              void* d_out, int out_size, void* d_ws, size_t ws_size,
                              hipStream_t stream) {
    const float* q    = (const float*)d_in[0];
    const float* k    = (const float*)d_in[1];
    const float* vals = (const float*)d_in[2];
    const float* vvec = (const float*)d_in[3];
    const float* mask = (const float*)d_in[4];
    const float* klen = (const float*)d_in[5];
    float* outp = (float*)d_out;

    float* ws = (float*)d_ws;
    prep_kernel<<<dim3(768), dim3(256), 0, stream>>>(q, k, vals, ws);

    const float* ws_ekf = (const float*)((char*)d_ws + WS_EK_OFF);
    const float* ws_eqf = (const float*)((char*)d_ws + WS_EQ_OFF);
    const unsigned short* ws_vt = (const unsigned short*)((char*)d_ws + WS_VT_OFF);
    addattn_kernel<<<dim3(BB * HH * (LL / 4)), dim3(256), 0, stream>>>(
        ws_ekf, ws_eqf, ws_vt, vvec, mask, klen, outp);
}